// Round 1
// baseline (3493.616 us; speedup 1.0000x reference)
//
#include <hip/hip_runtime.h>
#include <hip/hip_bf16.h>
#include <math.h>

#define D 256
#define NB 10000   // B graphs
#define NN 500000  // N nodes

// ---------------- K0: segment offsets via binary search on sorted batch ----
__global__ void segstart_kernel(const int* __restrict__ batch, int* __restrict__ seg_start,
                                int N, int B) {
    int b = blockIdx.x * blockDim.x + threadIdx.x;
    if (b > B) return;
    int lo = 0, hi = N;
    while (lo < hi) {
        int mid = (lo + hi) >> 1;
        if (batch[mid] < b) lo = mid + 1; else hi = mid;
    }
    seg_start[b] = lo;
}

// ---------------- K1: gate[n] = x[n] . W_gate + b_gate ---------------------
__global__ __launch_bounds__(256) void gate_kernel(const float* __restrict__ x,
                                                   const float* __restrict__ Wg,
                                                   const float* __restrict__ bg,
                                                   float* __restrict__ gate, int N) {
    int wave = threadIdx.x >> 6;
    int lane = threadIdx.x & 63;
    int n = blockIdx.x * 4 + wave;
    if (n >= N) return;
    const float4 xv = *(const float4*)(x + (size_t)n * D + lane * 4);
    const float4 wv = *(const float4*)(Wg + lane * 4);
    float d = xv.x * wv.x + xv.y * wv.y + xv.z * wv.z + xv.w * wv.w;
    #pragma unroll
    for (int off = 32; off > 0; off >>= 1) d += __shfl_down(d, off, 64);
    if (lane == 0) gate[n] = d + bg[0];
}

// ---------------- K2: per-graph softmax + feat matvec + weighted sum -------
// One block (256 threads) per graph. Thread t owns output column t.
__global__ __launch_bounds__(256) void seg_attn_kernel(
    const float* __restrict__ x, const float* __restrict__ Wf,
    const float* __restrict__ bf, const float* __restrict__ gate,
    const int* __restrict__ seg_start, float* __restrict__ xg) {
    const int b = blockIdx.x;
    const int t = threadIdx.x;
    const int s0 = seg_start[b];
    const int S  = seg_start[b + 1] - s0;

    __shared__ float red[256];

    // ---- softmax stats over the segment's gate values ----
    float lmax = -INFINITY;
    for (int i = t; i < S; i += 256) lmax = fmaxf(lmax, gate[s0 + i]);
    red[t] = lmax; __syncthreads();
    #pragma unroll
    for (int off = 128; off > 0; off >>= 1) {
        if (t < off) red[t] = fmaxf(red[t], red[t + off]);
        __syncthreads();
    }
    const float m = red[0]; __syncthreads();

    float lsum = 0.f;
    for (int i = t; i < S; i += 256) lsum += __expf(gate[s0 + i] - m);
    red[t] = lsum; __syncthreads();
    #pragma unroll
    for (int off = 128; off > 0; off >>= 1) {
        if (t < off) red[t] += red[t + off];
        __syncthreads();
    }
    const float inv_s = (S > 0) ? 1.0f / red[0] : 0.f;

    const float bft = bf[t];
    float xg_acc = 0.f;
    const char* xb = (const char*)x;

    // ---- node chunks of 16 ----
    for (int c0 = 0; c0 < S; c0 += 16) {
        unsigned rowoff[16];
        float acc[16];
        #pragma unroll
        for (int j = 0; j < 16; j++) {
            int idx = c0 + j;
            int r = (idx < S) ? idx : 0;  // clamp tail; weighted 0 below
            rowoff[j] = (unsigned)(s0 + r) * (unsigned)(D * 4);
            acc[j] = 0.f;
        }
        for (int k = 0; k < D; k += 4) {
            const float w0 = Wf[(k + 0) * D + t];
            const float w1 = Wf[(k + 1) * D + t];
            const float w2 = Wf[(k + 2) * D + t];
            const float w3 = Wf[(k + 3) * D + t];
            #pragma unroll
            for (int j = 0; j < 16; j++) {
                const float4 xv = *(const float4*)(xb + rowoff[j] + (unsigned)(k * 4));
                acc[j] = fmaf(xv.x, w0, acc[j]);
                acc[j] = fmaf(xv.y, w1, acc[j]);
                acc[j] = fmaf(xv.z, w2, acc[j]);
                acc[j] = fmaf(xv.w, w3, acc[j]);
            }
        }
        #pragma unroll
        for (int j = 0; j < 16; j++) {
            int idx = c0 + j;
            if (idx < S) {
                float a = __expf(gate[s0 + idx] - m) * inv_s;
                float y = acc[j] + bft;
                y = (y >= 0.f) ? y : 0.01f * y;
                xg_acc = fmaf(a, y, xg_acc);
            }
        }
    }
    xg[(size_t)b * D + t] = xg_acc;
}

// ---------------- K3: out = leaky([xg, xg_old] @ W_t + b_t) + xg_old -------
// 8 rows per block; thread t owns output column t.
__global__ __launch_bounds__(256) void out_kernel(
    const float* __restrict__ xg, const float* __restrict__ xg_old,
    const float* __restrict__ Wt, const float* __restrict__ bt,
    float* __restrict__ out) {
    const int t = threadIdx.x;
    const int r0 = blockIdx.x * 8;
    float acc[8];
    #pragma unroll
    for (int r = 0; r < 8; r++) acc[r] = 0.f;

    for (int k = 0; k < D; k++) {
        const float w = Wt[k * D + t];
        #pragma unroll
        for (int r = 0; r < 8; r++)
            acc[r] = fmaf(xg[(size_t)(r0 + r) * D + k], w, acc[r]);
    }
    for (int k = 0; k < D; k++) {
        const float w = Wt[(D + k) * D + t];
        #pragma unroll
        for (int r = 0; r < 8; r++)
            acc[r] = fmaf(xg_old[(size_t)(r0 + r) * D + k], w, acc[r]);
    }
    const float btt = bt[t];
    #pragma unroll
    for (int r = 0; r < 8; r++) {
        float y = acc[r] + btt;
        y = (y >= 0.f) ? y : 0.01f * y;
        out[(size_t)(r0 + r) * D + t] = y + xg_old[(size_t)(r0 + r) * D + t];
    }
}

// ---------------------------------------------------------------------------
extern "C" void kernel_launch(void* const* d_in, const int* in_sizes, int n_in,
                              void* d_out, int out_size, void* d_ws, size_t ws_size,
                              hipStream_t stream) {
    const float* xg_old = (const float*)d_in[0];   // [B, D]
    const float* x      = (const float*)d_in[1];   // [N, D]
    const int*   batch  = (const int*)d_in[2];     // [N], sorted
    const float* W_gate = (const float*)d_in[3];   // [D]
    const float* b_gate = (const float*)d_in[4];   // [1]
    const float* W_feat = (const float*)d_in[5];   // [D, D]
    const float* b_feat = (const float*)d_in[6];   // [D]
    const float* W_t    = (const float*)d_in[7];   // [2D, D]
    const float* b_t    = (const float*)d_in[8];   // [D]
    float* out = (float*)d_out;                    // [B, D]

    const int N = in_sizes[1] / D;                 // 500000
    const int B = in_sizes[0] / D;                 // 10000

    // workspace layout (ws re-poisoned each call; everything below is fully
    // written before being read)
    char* ws = (char*)d_ws;
    int*   seg_start = (int*)ws;                        // (B+1) ints
    float* gate      = (float*)(ws + (1 << 16));        // N floats @ 64 KiB
    float* xg        = (float*)(ws + (4 << 20));        // B*D floats @ 4 MiB

    segstart_kernel<<<(B + 1 + 255) / 256, 256, 0, stream>>>(batch, seg_start, N, B);
    gate_kernel<<<(N + 3) / 4, 256, 0, stream>>>(x, W_gate, b_gate, gate, N);
    seg_attn_kernel<<<B, 256, 0, stream>>>(x, W_feat, b_feat, gate, seg_start, xg);
    out_kernel<<<B / 8, 256, 0, stream>>>(xg, xg_old, W_t, b_t, out);
}

// Round 2
// 1105.934 us; speedup vs baseline: 3.1590x; 3.1590x over previous
//
#include <hip/hip_runtime.h>
#include <hip/hip_bf16.h>
#include <math.h>

#define D 256

typedef short v8s __attribute__((ext_vector_type(8)));
typedef float f32x4 __attribute__((ext_vector_type(4)));

// ---------------- K0: segment offsets via binary search on sorted batch ----
__global__ void segstart_kernel(const int* __restrict__ batch, int* __restrict__ seg_start,
                                int N, int B) {
    int b = blockIdx.x * blockDim.x + threadIdx.x;
    if (b > B) return;
    int lo = 0, hi = N;
    while (lo < hi) {
        int mid = (lo + hi) >> 1;
        if (batch[mid] < b) lo = mid + 1; else hi = mid;
    }
    seg_start[b] = lo;
}

// ---------------- K1: gate[n] = x[n] . W_gate + b_gate ---------------------
__global__ __launch_bounds__(256) void gate_kernel(const float* __restrict__ x,
                                                   const float* __restrict__ Wg,
                                                   const float* __restrict__ bg,
                                                   float* __restrict__ gate, int N) {
    int wave = threadIdx.x >> 6;
    int lane = threadIdx.x & 63;
    int n = blockIdx.x * 4 + wave;
    if (n >= N) return;
    const float4 xv = *(const float4*)(x + (size_t)n * D + lane * 4);
    const float4 wv = *(const float4*)(Wg + lane * 4);
    float d = xv.x * wv.x + xv.y * wv.y + xv.z * wv.z + xv.w * wv.w;
    #pragma unroll
    for (int off = 32; off > 0; off >>= 1) d += __shfl_down(d, off, 64);
    if (lane == 0) gate[n] = d + bg[0];
}

// ---------------- K1b: per-graph softmax stats (max, 1/sum) ----------------
__global__ __launch_bounds__(256) void stats_kernel(const float* __restrict__ gate,
                                                    const int* __restrict__ seg_start,
                                                    float* __restrict__ mvec,
                                                    float* __restrict__ invs, int B) {
    int wid = blockIdx.x * 4 + (threadIdx.x >> 6);
    int lane = threadIdx.x & 63;
    if (wid >= B) return;
    int s0 = seg_start[wid], s1 = seg_start[wid + 1];
    float m = -INFINITY;
    for (int i = s0 + lane; i < s1; i += 64) m = fmaxf(m, gate[i]);
    #pragma unroll
    for (int off = 32; off > 0; off >>= 1) m = fmaxf(m, __shfl_xor(m, off, 64));
    float s = 0.f;
    for (int i = s0 + lane; i < s1; i += 64) s += __expf(gate[i] - m);
    #pragma unroll
    for (int off = 32; off > 0; off >>= 1) s += __shfl_xor(s, off, 64);
    if (lane == 0) { mvec[wid] = m; invs[wid] = (s > 0.f) ? 1.f / s : 0.f; }
}

// ---------------- K0b: W_feat -> bf16 in MFMA B-fragment order -------------
// B frag (16x16x32): value W[k][n] at lane = ((k>>3)&3)*16 + (n&15), reg j = k&7.
// Tile index: (n_tile = n>>4, k_step = k>>5). Contiguous per-lane 8 elements.
__global__ void wconv_kernel(const float* __restrict__ Wf, unsigned short* __restrict__ Wb) {
    int idx = blockIdx.x * 256 + threadIdx.x;   // 65536 total
    int k = idx >> 8, n = idx & 255;
    int n_tile = n >> 4, k_step = k >> 5;
    int lane = ((k >> 3) & 3) * 16 + (n & 15);
    int j = k & 7;
    int dst = (((n_tile * 8 + k_step) * 64) + lane) * 8 + j;
    Wb[dst] = __bfloat16_as_ushort(__float2bfloat16(Wf[k * 256 + n]));
}

// ---------------- K2: MFMA feat GEMM fused with softmax-weighted segsum ----
// Block = 64 nodes x 256 cols; 4 waves, wave w owns cols [w*64, w*64+64).
__global__ __launch_bounds__(256) void feat_attn_kernel(
    const float* __restrict__ x, const unsigned short* __restrict__ Wb,
    const float* __restrict__ bfeat, const float* __restrict__ gate,
    const int* __restrict__ batch, const float* __restrict__ mvec,
    const float* __restrict__ invs, float* __restrict__ xg, int N) {

    __shared__ unsigned short feat_s[64 * 260];  // bf16 post-bias/leaky, padded stride
    __shared__ float alpha_s[64];
    __shared__ int batch_s[64];

    const int tid = threadIdx.x;
    const int n0 = blockIdx.x * 64;
    const int cnt = min(64, N - n0);

    if (tid < 64) {
        if (tid < cnt) {
            int n = n0 + tid;
            int b = batch[n];
            batch_s[tid] = b;
            alpha_s[tid] = __expf(gate[n] - mvec[b]) * invs[b];
        } else { batch_s[tid] = -1; alpha_s[tid] = 0.f; }
    }

    const int w = tid >> 6, lane = tid & 63;
    const int mrow = lane & 15, q = lane >> 4;

    f32x4 acc[4][4];
    #pragma unroll
    for (int i = 0; i < 4; i++)
        #pragma unroll
        for (int j = 0; j < 4; j++) acc[i][j] = (f32x4){0.f, 0.f, 0.f, 0.f};

    size_t rowbase[4];
    #pragma unroll
    for (int rb = 0; rb < 4; rb++) {
        int r = n0 + rb * 16 + mrow;
        if (r > N - 1) r = N - 1;
        rowbase[rb] = (size_t)r * D + q * 8;
    }

    for (int ks = 0; ks < 8; ks++) {
        v8s a[4], bfr[4];
        #pragma unroll
        for (int rb = 0; rb < 4; rb++) {
            const float* p = x + rowbase[rb] + ks * 32;
            float4 f0 = *(const float4*)p;
            float4 f1 = *(const float4*)(p + 4);
            v8s v;
            v[0] = (short)__bfloat16_as_ushort(__float2bfloat16(f0.x));
            v[1] = (short)__bfloat16_as_ushort(__float2bfloat16(f0.y));
            v[2] = (short)__bfloat16_as_ushort(__float2bfloat16(f0.z));
            v[3] = (short)__bfloat16_as_ushort(__float2bfloat16(f0.w));
            v[4] = (short)__bfloat16_as_ushort(__float2bfloat16(f1.x));
            v[5] = (short)__bfloat16_as_ushort(__float2bfloat16(f1.y));
            v[6] = (short)__bfloat16_as_ushort(__float2bfloat16(f1.z));
            v[7] = (short)__bfloat16_as_ushort(__float2bfloat16(f1.w));
            a[rb] = v;
        }
        #pragma unroll
        for (int cb = 0; cb < 4; cb++) {
            int nt = w * 4 + cb;
            bfr[cb] = *(const v8s*)(Wb + (((size_t)nt * 8 + ks) * 64 + lane) * 8);
        }
        #pragma unroll
        for (int rb = 0; rb < 4; rb++)
            #pragma unroll
            for (int cb = 0; cb < 4; cb++)
                acc[rb][cb] = __builtin_amdgcn_mfma_f32_16x16x32_bf16(
                    a[rb], bfr[cb], acc[rb][cb], 0, 0, 0);
    }

    // epilogue: bias + leaky, bf16 store to LDS (C/D: col=lane&15, row=q*4+reg)
    #pragma unroll
    for (int cb = 0; cb < 4; cb++) {
        int col = w * 64 + cb * 16 + mrow;
        float bias = bfeat[col];
        #pragma unroll
        for (int rb = 0; rb < 4; rb++) {
            #pragma unroll
            for (int reg = 0; reg < 4; reg++) {
                float y = acc[rb][cb][reg] + bias;
                y = (y >= 0.f) ? y : 0.01f * y;
                feat_s[(rb * 16 + q * 4 + reg) * 260 + col] =
                    __bfloat16_as_ushort(__float2bfloat16(y));
            }
        }
    }
    __syncthreads();

    // walk the sorted tile: one run-sum per (segment, col), atomic at boundary
    float sum = 0.f;
    int cur = batch_s[0];
    for (int i = 0; i < cnt; i++) {
        int b = batch_s[i];
        if (b != cur) {
            atomicAdd(&xg[(size_t)cur * D + tid], sum);
            sum = 0.f; cur = b;
        }
        float y = __bfloat162float(__ushort_as_bfloat16(feat_s[i * 260 + tid]));
        sum = fmaf(alpha_s[i], y, sum);
    }
    atomicAdd(&xg[(size_t)cur * D + tid], sum);
}

// ---------------- K3: out = leaky([xg, xg_old] @ W_t + b_t) + xg_old -------
__global__ __launch_bounds__(256) void out_kernel(
    const float* __restrict__ xg, const float* __restrict__ xg_old,
    const float* __restrict__ Wt, const float* __restrict__ bt,
    float* __restrict__ out) {
    const int t = threadIdx.x;
    const int r0 = blockIdx.x * 8;
    float acc[8];
    #pragma unroll
    for (int r = 0; r < 8; r++) acc[r] = 0.f;

    for (int k = 0; k < D; k++) {
        const float w = Wt[k * D + t];
        #pragma unroll
        for (int r = 0; r < 8; r++)
            acc[r] = fmaf(xg[(size_t)(r0 + r) * D + k], w, acc[r]);
    }
    for (int k = 0; k < D; k++) {
        const float w = Wt[(D + k) * D + t];
        #pragma unroll
        for (int r = 0; r < 8; r++)
            acc[r] = fmaf(xg_old[(size_t)(r0 + r) * D + k], w, acc[r]);
    }
    const float btt = bt[t];
    #pragma unroll
    for (int r = 0; r < 8; r++) {
        float y = acc[r] + btt;
        y = (y >= 0.f) ? y : 0.01f * y;
        out[(size_t)(r0 + r) * D + t] = y + xg_old[(size_t)(r0 + r) * D + t];
    }
}

// ---------------------------------------------------------------------------
extern "C" void kernel_launch(void* const* d_in, const int* in_sizes, int n_in,
                              void* d_out, int out_size, void* d_ws, size_t ws_size,
                              hipStream_t stream) {
    const float* xg_old = (const float*)d_in[0];   // [B, D]
    const float* x      = (const float*)d_in[1];   // [N, D]
    const int*   batch  = (const int*)d_in[2];     // [N], sorted
    const float* W_gate = (const float*)d_in[3];   // [D]
    const float* b_gate = (const float*)d_in[4];   // [1]
    const float* W_feat = (const float*)d_in[5];   // [D, D]
    const float* b_feat = (const float*)d_in[6];   // [D]
    const float* W_t    = (const float*)d_in[7];   // [2D, D]
    const float* b_t    = (const float*)d_in[8];   // [D]
    float* out = (float*)d_out;                    // [B, D]

    const int N = in_sizes[1] / D;                 // 500000
    const int B = in_sizes[0] / D;                 // 10000

    // workspace layout (~12.9 MB total)
    char* ws = (char*)d_ws;
    int*            seg_start = (int*)ws;                       // (B+1) ints
    float*          gate      = (float*)(ws + 0x10000);         // N floats  (2 MB)
    float*          mvec      = (float*)(ws + 0x220000);        // B floats
    float*          invs      = (float*)(ws + 0x230000);        // B floats
    unsigned short* Wb        = (unsigned short*)(ws + 0x240000); // 65536 bf16 (128 KB)
    float*          xg        = (float*)(ws + 0x280000);        // B*D floats (10.24 MB)

    segstart_kernel<<<(B + 1 + 255) / 256, 256, 0, stream>>>(batch, seg_start, N, B);
    gate_kernel<<<(N + 3) / 4, 256, 0, stream>>>(x, W_gate, b_gate, gate, N);
    stats_kernel<<<(B + 3) / 4, 256, 0, stream>>>(gate, seg_start, mvec, invs, B);
    wconv_kernel<<<256, 256, 0, stream>>>(W_feat, Wb);
    hipMemsetAsync(xg, 0, (size_t)B * D * sizeof(float), stream);
    feat_attn_kernel<<<(N + 63) / 64, 256, 0, stream>>>(
        x, Wb, b_feat, gate, batch, mvec, invs, xg, N);
    out_kernel<<<B / 8, 256, 0, stream>>>(xg, xg_old, W_t, b_t, out);
}

// Round 3
// 988.030 us; speedup vs baseline: 3.5359x; 1.1193x over previous
//
#include <hip/hip_runtime.h>
#include <hip/hip_bf16.h>
#include <math.h>

#define D 256

typedef short v8s __attribute__((ext_vector_type(8)));
typedef float f32x4 __attribute__((ext_vector_type(4)));

__device__ __forceinline__ unsigned short f2b(float f) {
    return __bfloat16_as_ushort(__float2bfloat16(f));
}

// ---------------- K0: segment offsets via binary search on sorted batch ----
__global__ void segstart_kernel(const int* __restrict__ batch, int* __restrict__ seg_start,
                                int N, int B) {
    int b = blockIdx.x * blockDim.x + threadIdx.x;
    if (b > B) return;
    int lo = 0, hi = N;
    while (lo < hi) {
        int mid = (lo + hi) >> 1;
        if (batch[mid] < b) lo = mid + 1; else hi = mid;
    }
    seg_start[b] = lo;
}

// ---------------- K1: gate = x.Wg + bg, optionally emit bf16 copy of x -----
// Grid-strided, one wave per node per iteration.
template<bool CONV>
__global__ __launch_bounds__(256) void gate_conv_kernel(
    const float* __restrict__ x, const float* __restrict__ Wg,
    const float* __restrict__ bg, float* __restrict__ gate,
    unsigned short* __restrict__ xb16, int N) {
    const int lane = threadIdx.x & 63;
    const int wid = blockIdx.x * 4 + (threadIdx.x >> 6);
    const int nw = gridDim.x * 4;
    const float4 wv = *(const float4*)(Wg + lane * 4);
    const float bgv = bg[0];
    for (int n = wid; n < N; n += nw) {
        const float4 xv = *(const float4*)(x + (size_t)n * D + lane * 4);
        if (CONV) {
            ushort4 h = { f2b(xv.x), f2b(xv.y), f2b(xv.z), f2b(xv.w) };
            *(ushort4*)(xb16 + (size_t)n * D + lane * 4) = h;
        }
        float d = xv.x * wv.x + xv.y * wv.y + xv.z * wv.z + xv.w * wv.w;
        #pragma unroll
        for (int off = 32; off; off >>= 1) d += __shfl_xor(d, off, 64);
        if (lane == 0) gate[n] = d + bgv;
    }
}

// ---------------- K1b: per-graph softmax stats (max, 1/sum) ----------------
__global__ __launch_bounds__(256) void stats_kernel(const float* __restrict__ gate,
                                                    const int* __restrict__ seg_start,
                                                    float* __restrict__ mvec,
                                                    float* __restrict__ invs, int B) {
    int wid = blockIdx.x * 4 + (threadIdx.x >> 6);
    int lane = threadIdx.x & 63;
    if (wid >= B) return;
    int s0 = seg_start[wid], s1 = seg_start[wid + 1];
    float m = -INFINITY;
    for (int i = s0 + lane; i < s1; i += 64) m = fmaxf(m, gate[i]);
    #pragma unroll
    for (int off = 32; off > 0; off >>= 1) m = fmaxf(m, __shfl_xor(m, off, 64));
    float s = 0.f;
    for (int i = s0 + lane; i < s1; i += 64) s += __expf(gate[i] - m);
    #pragma unroll
    for (int off = 32; off > 0; off >>= 1) s += __shfl_xor(s, off, 64);
    if (lane == 0) { mvec[wid] = m; invs[wid] = (s > 0.f) ? 1.f / s : 0.f; }
}

// ---------------- W -> bf16 in MFMA B-fragment order (K x 256) -------------
// B frag (16x16x32): W[k][n] at lane = ((k>>3)&3)*16 + (n&15), reg j = k&7.
__global__ void wconv_kernel(const float* __restrict__ Wf, unsigned short* __restrict__ Wb,
                             int K) {
    int idx = blockIdx.x * 256 + threadIdx.x;   // K*256 total
    int k = idx >> 8, n = idx & 255;
    if (k >= K) return;
    int n_tile = n >> 4, k_step = k >> 5, ksteps = K >> 5;
    int lane = ((k >> 3) & 3) * 16 + (n & 15);
    int j = k & 7;
    int dst = (((n_tile * ksteps + k_step) * 64) + lane) * 8 + j;
    Wb[dst] = f2b(Wf[k * 256 + n]);
}

// ---------------- K2: MFMA feat GEMM fused with softmax-weighted segsum ----
// Block = 64 nodes x 256 cols; 4 waves, wave w owns cols [w*64, w*64+64).
template<bool BF16IN>
__global__ __launch_bounds__(256) void feat_attn_kernel(
    const float* __restrict__ x, const unsigned short* __restrict__ xb16,
    const unsigned short* __restrict__ Wb,
    const float* __restrict__ bfeat, const float* __restrict__ gate,
    const int* __restrict__ batch, const float* __restrict__ mvec,
    const float* __restrict__ invs, float* __restrict__ xg, int N) {

    __shared__ unsigned short feat_s[64 * 260];
    __shared__ float alpha_s[64];
    __shared__ int batch_s[64];

    const int tid = threadIdx.x;
    const int n0 = blockIdx.x * 64;
    const int cnt = min(64, N - n0);

    if (tid < 64) {
        if (tid < cnt) {
            int n = n0 + tid;
            int b = batch[n];
            batch_s[tid] = b;
            alpha_s[tid] = __expf(gate[n] - mvec[b]) * invs[b];
        } else { batch_s[tid] = -1; alpha_s[tid] = 0.f; }
    }

    const int w = tid >> 6, lane = tid & 63;
    const int mrow = lane & 15, q = lane >> 4;

    f32x4 acc[4][4];
    #pragma unroll
    for (int i = 0; i < 4; i++)
        #pragma unroll
        for (int j = 0; j < 4; j++) acc[i][j] = (f32x4){0.f, 0.f, 0.f, 0.f};

    size_t rowbase[4];
    #pragma unroll
    for (int rb = 0; rb < 4; rb++) {
        int r = n0 + rb * 16 + mrow;
        if (r > N - 1) r = N - 1;
        rowbase[rb] = (size_t)r * D + q * 8;
    }

    for (int ks = 0; ks < 8; ks++) {
        v8s a[4], bfr[4];
        #pragma unroll
        for (int rb = 0; rb < 4; rb++) {
            if (BF16IN) {
                a[rb] = *(const v8s*)(xb16 + rowbase[rb] + ks * 32);
            } else {
                const float* p = x + rowbase[rb] + ks * 32;
                float4 f0 = *(const float4*)p;
                float4 f1 = *(const float4*)(p + 4);
                v8s v;
                v[0] = (short)f2b(f0.x); v[1] = (short)f2b(f0.y);
                v[2] = (short)f2b(f0.z); v[3] = (short)f2b(f0.w);
                v[4] = (short)f2b(f1.x); v[5] = (short)f2b(f1.y);
                v[6] = (short)f2b(f1.z); v[7] = (short)f2b(f1.w);
                a[rb] = v;
            }
        }
        #pragma unroll
        for (int cb = 0; cb < 4; cb++) {
            int nt = w * 4 + cb;
            bfr[cb] = *(const v8s*)(Wb + (((size_t)nt * 8 + ks) * 64 + lane) * 8);
        }
        #pragma unroll
        for (int rb = 0; rb < 4; rb++)
            #pragma unroll
            for (int cb = 0; cb < 4; cb++)
                acc[rb][cb] = __builtin_amdgcn_mfma_f32_16x16x32_bf16(
                    a[rb], bfr[cb], acc[rb][cb], 0, 0, 0);
    }

    // epilogue: bias + leaky -> bf16 LDS (C/D: col=lane&15, row=q*4+reg)
    #pragma unroll
    for (int cb = 0; cb < 4; cb++) {
        int col = w * 64 + cb * 16 + mrow;
        float bias = bfeat[col];
        #pragma unroll
        for (int rb = 0; rb < 4; rb++) {
            #pragma unroll
            for (int reg = 0; reg < 4; reg++) {
                float y = acc[rb][cb][reg] + bias;
                y = (y >= 0.f) ? y : 0.01f * y;
                feat_s[(rb * 16 + q * 4 + reg) * 260 + col] = f2b(y);
            }
        }
    }
    __syncthreads();

    // walk the sorted tile: one run-sum per (segment, col), atomic at boundary
    float sum = 0.f;
    int cur = batch_s[0];
    for (int i = 0; i < cnt; i++) {
        int b = batch_s[i];
        if (b != cur) {
            atomicAdd(&xg[(size_t)cur * D + tid], sum);
            sum = 0.f; cur = b;
        }
        float y = __bfloat162float(__ushort_as_bfloat16(feat_s[i * 260 + tid]));
        sum = fmaf(alpha_s[i], y, sum);
    }
    atomicAdd(&xg[(size_t)cur * D + tid], sum);
}

// ---------------- cat = [xg, xg_old] -> bf16 -------------------------------
__global__ void catconv_kernel(const float* __restrict__ xg, const float* __restrict__ xg_old,
                               unsigned short* __restrict__ catb, int B) {
    int idx = blockIdx.x * 256 + threadIdx.x;  // B*64
    if (idx >= B * 64) return;
    int b = idx >> 6, c = (idx & 63) * 4;
    float4 v1 = *(const float4*)(xg + (size_t)b * D + c);
    float4 v2 = *(const float4*)(xg_old + (size_t)b * D + c);
    ushort4 h1 = { f2b(v1.x), f2b(v1.y), f2b(v1.z), f2b(v1.w) };
    ushort4 h2 = { f2b(v2.x), f2b(v2.y), f2b(v2.z), f2b(v2.w) };
    *(ushort4*)(catb + (size_t)b * 512 + c) = h1;
    *(ushort4*)(catb + (size_t)b * 512 + 256 + c) = h2;
}

// ---------------- K3 (MFMA): out = leaky(cat @ W_t + b_t) + xg_old ---------
__global__ __launch_bounds__(256) void out_mfma_kernel(
    const unsigned short* __restrict__ catb, const unsigned short* __restrict__ Wtb,
    const float* __restrict__ bt, const float* __restrict__ xg_old,
    float* __restrict__ out, int B) {
    const int tid = threadIdx.x;
    const int w = tid >> 6, lane = tid & 63, mrow = lane & 15, q = lane >> 4;
    const int r0 = blockIdx.x * 64;

    f32x4 acc[4][4];
    #pragma unroll
    for (int i = 0; i < 4; i++)
        #pragma unroll
        for (int j = 0; j < 4; j++) acc[i][j] = (f32x4){0.f, 0.f, 0.f, 0.f};

    size_t rowbase[4];
    #pragma unroll
    for (int rb = 0; rb < 4; rb++) {
        int r = r0 + rb * 16 + mrow;
        if (r > B - 1) r = B - 1;
        rowbase[rb] = (size_t)r * 512 + q * 8;
    }

    for (int ks = 0; ks < 16; ks++) {
        v8s a[4], bfr[4];
        #pragma unroll
        for (int rb = 0; rb < 4; rb++)
            a[rb] = *(const v8s*)(catb + rowbase[rb] + ks * 32);
        #pragma unroll
        for (int cb = 0; cb < 4; cb++)
            bfr[cb] = *(const v8s*)(Wtb + (((size_t)(w * 4 + cb) * 16 + ks) * 64 + lane) * 8);
        #pragma unroll
        for (int rb = 0; rb < 4; rb++)
            #pragma unroll
            for (int cb = 0; cb < 4; cb++)
                acc[rb][cb] = __builtin_amdgcn_mfma_f32_16x16x32_bf16(
                    a[rb], bfr[cb], acc[rb][cb], 0, 0, 0);
    }

    #pragma unroll
    for (int cb = 0; cb < 4; cb++) {
        int col = w * 64 + cb * 16 + mrow;
        float bias = bt[col];
        #pragma unroll
        for (int rb = 0; rb < 4; rb++) {
            #pragma unroll
            for (int reg = 0; reg < 4; reg++) {
                int row = r0 + rb * 16 + q * 4 + reg;
                if (row < B) {
                    float y = acc[rb][cb][reg] + bias;
                    y = (y >= 0.f) ? y : 0.01f * y;
                    out[(size_t)row * D + col] = y + xg_old[(size_t)row * D + col];
                }
            }
        }
    }
}

// ---------------- K3 (fp32 fallback) ---------------------------------------
__global__ __launch_bounds__(256) void out_kernel(
    const float* __restrict__ xg, const float* __restrict__ xg_old,
    const float* __restrict__ Wt, const float* __restrict__ bt,
    float* __restrict__ out) {
    const int t = threadIdx.x;
    const int r0 = blockIdx.x * 8;
    float acc[8];
    #pragma unroll
    for (int r = 0; r < 8; r++) acc[r] = 0.f;
    for (int k = 0; k < D; k++) {
        const float w = Wt[k * D + t];
        #pragma unroll
        for (int r = 0; r < 8; r++)
            acc[r] = fmaf(xg[(size_t)(r0 + r) * D + k], w, acc[r]);
    }
    for (int k = 0; k < D; k++) {
        const float w = Wt[(D + k) * D + t];
        #pragma unroll
        for (int r = 0; r < 8; r++)
            acc[r] = fmaf(xg_old[(size_t)(r0 + r) * D + k], w, acc[r]);
    }
    const float btt = bt[t];
    #pragma unroll
    for (int r = 0; r < 8; r++) {
        float y = acc[r] + btt;
        y = (y >= 0.f) ? y : 0.01f * y;
        out[(size_t)(r0 + r) * D + t] = y + xg_old[(size_t)(r0 + r) * D + t];
    }
}

// ---------------------------------------------------------------------------
extern "C" void kernel_launch(void* const* d_in, const int* in_sizes, int n_in,
                              void* d_out, int out_size, void* d_ws, size_t ws_size,
                              hipStream_t stream) {
    const float* xg_old = (const float*)d_in[0];   // [B, D]
    const float* x      = (const float*)d_in[1];   // [N, D]
    const int*   batch  = (const int*)d_in[2];     // [N], sorted
    const float* W_gate = (const float*)d_in[3];   // [D]
    const float* b_gate = (const float*)d_in[4];   // [1]
    const float* W_feat = (const float*)d_in[5];   // [D, D]
    const float* b_feat = (const float*)d_in[6];   // [D]
    const float* W_t    = (const float*)d_in[7];   // [2D, D]
    const float* b_t    = (const float*)d_in[8];   // [D]
    float* out = (float*)d_out;                    // [B, D]

    const int N = in_sizes[1] / D;                 // 500000
    const int B = in_sizes[0] / D;                 // 10000

    // workspace layout
    char* ws = (char*)d_ws;
    int*            seg_start = (int*)ws;                         // 40 KB
    float*          gate      = (float*)(ws + 0x10000);           // 2 MB
    float*          mvec      = (float*)(ws + 0x220000);          // 40 KB
    float*          invs      = (float*)(ws + 0x230000);          // 40 KB
    unsigned short* Wb        = (unsigned short*)(ws + 0x240000); // 128 KB
    unsigned short* Wtb       = (unsigned short*)(ws + 0x260000); // 256 KB
    float*          xg        = (float*)(ws + 0x2A0000);          // 10.24 MB
    unsigned short* catb      = (unsigned short*)(ws + 0xCA0000); // 10.24 MB
    unsigned short* xb16      = (unsigned short*)(ws + 0x16A0000);// 256 MB

    const size_t need_full = 0x16A0000 + (size_t)N * D * 2;       // ~280 MB
    const size_t need_mid  = 0x16A0000;                           // ~23.7 MB
    const bool full = ws_size >= need_full;
    const bool mid  = ws_size >= need_mid;

    segstart_kernel<<<(B + 1 + 255) / 256, 256, 0, stream>>>(batch, seg_start, N, B);
    if (full)
        gate_conv_kernel<true><<<2048, 256, 0, stream>>>(x, W_gate, b_gate, gate, xb16, N);
    else
        gate_conv_kernel<false><<<2048, 256, 0, stream>>>(x, W_gate, b_gate, gate, xb16, N);
    stats_kernel<<<(B + 3) / 4, 256, 0, stream>>>(gate, seg_start, mvec, invs, B);
    wconv_kernel<<<256, 256, 0, stream>>>(W_feat, Wb, 256);
    if (mid) wconv_kernel<<<512, 256, 0, stream>>>(W_t, Wtb, 512);
    hipMemsetAsync(xg, 0, (size_t)B * D * sizeof(float), stream);

    if (full)
        feat_attn_kernel<true><<<(N + 63) / 64, 256, 0, stream>>>(
            x, xb16, Wb, b_feat, gate, batch, mvec, invs, xg, N);
    else
        feat_attn_kernel<false><<<(N + 63) / 64, 256, 0, stream>>>(
            x, xb16, Wb, b_feat, gate, batch, mvec, invs, xg, N);

    if (mid) {
        catconv_kernel<<<(B * 64 + 255) / 256, 256, 0, stream>>>(xg, xg_old, catb, B);
        out_mfma_kernel<<<(B + 63) / 64, 256, 0, stream>>>(catb, Wtb, b_t, xg_old, out, B);
    } else {
        out_kernel<<<B / 8, 256, 0, stream>>>(xg, xg_old, W_t, b_t, out);
    }
}